// Round 3
// baseline (367.681 us; speedup 1.0000x reference)
//
#include <hip/hip_runtime.h>
#include <hip/hip_bf16.h>

// All inputs and the output are float32 (verified round 1->2: bf16 interpretation
// gave NaN, f32 interpretation gave finite; reference dtypes are all jnp.float32).

__device__ __forceinline__ float leaky(float v) { return v >= 0.f ? v : 0.2f * v; }

struct GemmArgs {
    const float* W[4];
    const float* bias[4];
    int gstart[5];
    int in_roff[4];
    int rmul[4];
    int wstride[4];
};

// ---------- precompute rank_emb @ rm_w1[:,256:,:] + rm_b1 (batch-independent bias) ----------
__global__ void prebias_kernel(const float* __restrict__ rank_emb,
                               const float* __restrict__ rm_w1,
                               const float* __restrict__ rm_b1,
                               float* __restrict__ re_bias) {
    const int r = blockIdx.x, h = threadIdx.x;
    __shared__ float re[256];
    re[h] = rank_emb[r * 256 + h];
    __syncthreads();
    float acc = rm_b1[r * 256 + h];
    const float* w = rm_w1 + ((size_t)r * 512 + 256) * 256 + h;
    #pragma unroll 8
    for (int d = 0; d < 256; ++d) acc += re[d] * w[(size_t)d * 256];
    re_bias[r * 256 + h] = acc;
}

// ---------- generic batched layer: out[b, y, n] (+)= sum_k in[b, r_in, k] * W[rw, k, n] (+ bias at z==0)
// block 256 = 16 nq x 16 bq, tile 64b x 64n, thread 4x4. split-K over z, atomic f32 out.
template<bool IN_LEAKY>
__global__ __launch_bounds__(256, 2) void gemm_kernel(
    const float* __restrict__ in, float* __restrict__ out,
    int K, int Kslice, int N, int in_bs, int out_bs, int out_rs, GemmArgs ga)
{
    __shared__ __align__(16) float a_lds[64][72];   // [k][b]
    __shared__ __align__(16) float w_lds[64][72];   // [k][n]
    const int tid = threadIdx.x;
    const int nq = tid & 15, bq = tid >> 4;
    const int n0 = blockIdx.x * 64;
    const int y = blockIdx.y;
    const int z = blockIdx.z;
    int g = 0;
    while (g < 3 && y >= ga.gstart[g + 1]) ++g;
    const int rw = y - ga.gstart[g];
    const int r_in = ga.in_roff[g] + rw * ga.rmul[g];
    const float* Wp = ga.W[g] + (size_t)rw * ga.wstride[g];
    const size_t in_base = (size_t)r_in * K;

    float acc[4][4];
    #pragma unroll
    for (int i = 0; i < 4; ++i)
        #pragma unroll
        for (int j = 0; j < 4; ++j) acc[i][j] = 0.f;
    if (z == 0) {
        #pragma unroll
        for (int j = 0; j < 4; ++j) {
            float bv = ga.bias[g][(size_t)rw * N + n0 + nq * 4 + j];
            #pragma unroll
            for (int i = 0; i < 4; ++i) acc[i][j] = bv;
        }
    }

    const int kbeg = z * Kslice;
    for (int k0 = kbeg; k0 < kbeg + Kslice; k0 += 64) {
        // stage A (64k x 64b)
        #pragma unroll
        for (int j = 0; j < 16; ++j) {
            int idx = tid + j * 256;
            int k = idx & 63, b = idx >> 6;
            float v = in[(size_t)b * in_bs + in_base + k0 + k];
            if (IN_LEAKY) v = leaky(v);
            a_lds[k][b] = v;
        }
        // stage W (64k x 64n)
        #pragma unroll
        for (int j = 0; j < 16; ++j) {
            int idx = tid + j * 256;
            int n = idx & 63, k = idx >> 6;
            w_lds[k][n] = Wp[(size_t)(k0 + k) * N + n0 + n];
        }
        __syncthreads();
        #pragma unroll 16
        for (int kk = 0; kk < 64; ++kk) {
            float4 a = *(const float4*)&a_lds[kk][bq * 4];
            float4 w = *(const float4*)&w_lds[kk][nq * 4];
            float av[4] = {a.x, a.y, a.z, a.w};
            float wv[4] = {w.x, w.y, w.z, w.w};
            #pragma unroll
            for (int i = 0; i < 4; ++i)
                #pragma unroll
                for (int j = 0; j < 4; ++j)
                    acc[i][j] += av[i] * wv[j];
        }
        __syncthreads();
    }
    #pragma unroll
    for (int i = 0; i < 4; ++i) {
        int b = bq * 4 + i;
        float* op = out + (size_t)b * out_bs + (size_t)y * out_rs + n0 + nq * 4;
        #pragma unroll
        for (int j = 0; j < 4; ++j) atomicAdd(op + j, acc[i][j]);
    }
}

// ---------- N=24 head output layer (K=256), block 128 = 8 nq x 16 bq ----------
template<bool IN_LEAKY>
__global__ __launch_bounds__(128, 2) void gemm24_kernel(
    const float* __restrict__ in, float* __restrict__ out,
    int Kslice, int in_bs, GemmArgs ga)
{
    __shared__ __align__(16) float a_lds[64][72];
    __shared__ __align__(16) float w_lds[64][36];
    const int tid = threadIdx.x;
    const int nq = tid & 7, bq = tid >> 3;   // nq<6 valid (24 cols)
    const int y = blockIdx.y, z = blockIdx.z;
    int g = 0;
    while (g < 3 && y >= ga.gstart[g + 1]) ++g;
    const int rw = y - ga.gstart[g];
    const int r_in = ga.in_roff[g] + rw;
    const float* Wp = ga.W[g] + (size_t)rw * ga.wstride[g];

    float acc[4][4];
    #pragma unroll
    for (int i = 0; i < 4; ++i)
        #pragma unroll
        for (int j = 0; j < 4; ++j) acc[i][j] = 0.f;
    if (z == 0 && nq < 6) {
        #pragma unroll
        for (int j = 0; j < 4; ++j) {
            float bv = ga.bias[g][(size_t)rw * 24 + nq * 4 + j];
            #pragma unroll
            for (int i = 0; i < 4; ++i) acc[i][j] = bv;
        }
    }
    const int kbeg = z * Kslice;
    for (int k0 = kbeg; k0 < kbeg + Kslice; k0 += 64) {
        #pragma unroll
        for (int j = 0; j < 32; ++j) {
            int idx = tid + j * 128;
            int k = idx & 63, b = idx >> 6;
            float v = in[(size_t)b * in_bs + (size_t)r_in * 256 + k0 + k];
            if (IN_LEAKY) v = leaky(v);
            a_lds[k][b] = v;
        }
        #pragma unroll
        for (int j = 0; j < 16; ++j) {
            int idx = tid + j * 128;
            int n = idx & 31, k = idx >> 5;
            w_lds[k][n] = (n < 24) ? Wp[(size_t)(k0 + k) * 24 + n] : 0.f;
        }
        __syncthreads();
        #pragma unroll 16
        for (int kk = 0; kk < 64; ++kk) {
            float4 a = *(const float4*)&a_lds[kk][bq * 4];
            float4 w = *(const float4*)&w_lds[kk][nq * 4];
            float av[4] = {a.x, a.y, a.z, a.w};
            float wv[4] = {w.x, w.y, w.z, w.w};
            #pragma unroll
            for (int i = 0; i < 4; ++i)
                #pragma unroll
                for (int j = 0; j < 4; ++j)
                    acc[i][j] += av[i] * wv[j];
        }
        __syncthreads();
    }
    if (nq < 6) {
        #pragma unroll
        for (int i = 0; i < 4; ++i) {
            int b = bq * 4 + i;
            float* op = out + (size_t)b * 1152 + y * 24 + nq * 4;
            #pragma unroll
            for (int j = 0; j < 4; ++j) atomicAdd(op + j, acc[i][j]);
        }
    }
}

// ---------- spline + softmax fold; Pcat rows: [Px_m 0..15, Py_m 16..31, Px_a 32..39, Py_a 40..47]
__global__ __launch_bounds__(512) void spline_kernel(
    const float* __restrict__ Pcat,
    const float* __restrict__ mult_w, const float* __restrict__ addx_w,
    const float* __restrict__ addy_w, const float* __restrict__ gbias,
    float* __restrict__ U, float* __restrict__ V,
    float* __restrict__ dxv, float* __restrict__ dyv)
{
    __shared__ float cp[48][25];
    __shared__ float sw[33];
    const int b = blockIdx.x, j = threadIdx.x;
    for (int idx = j; idx < 1152; idx += 512) cp[idx / 24][idx % 24] = Pcat[(size_t)b * 1152 + idx];
    if (j == 0) {
        float e[16], m, s;
        m = -1e30f; for (int i = 0; i < 16; ++i) m = fmaxf(m, mult_w[i]);
        s = 0.f;    for (int i = 0; i < 16; ++i) { e[i] = __expf(mult_w[i] - m); s += e[i]; }
        for (int i = 0; i < 16; ++i) sw[i] = e[i] / s;
        m = -1e30f; for (int i = 0; i < 8; ++i) m = fmaxf(m, addx_w[i]);
        s = 0.f;    for (int i = 0; i < 8; ++i) { e[i] = __expf(addx_w[i] - m); s += e[i]; }
        for (int i = 0; i < 8; ++i) sw[16 + i] = e[i] / s;
        m = -1e30f; for (int i = 0; i < 8; ++i) m = fmaxf(m, addy_w[i]);
        s = 0.f;    for (int i = 0; i < 8; ++i) { e[i] = __expf(addy_w[i] - m); s += e[i]; }
        for (int i = 0; i < 8; ++i) sw[24 + i] = e[i] / s;
        sw[32] = gbias[0];
    }
    __syncthreads();
    const float eps = 0.001f;
    float t = eps + (float)j * ((1.f - 2.f * eps) / 511.f);
    float ts = t * 23.f;
    int seg = (int)ts; if (seg > 22) seg = 22;
    float tau = ts - (float)seg;
    tau = fminf(fmaxf(tau, 0.f), 0.9999f);
    float t2 = tau * tau, t3 = t2 * tau;
    float h00 = 2.f * t3 - 3.f * t2 + 1.f;
    float h10 = t3 - 2.f * t2 + tau;
    float h01 = -2.f * t3 + 3.f * t2;
    float h11 = t3 - t2;
    int sm1 = seg > 0 ? seg - 1 : 0;
    int s1 = seg + 1;
    int sp2 = s1 < 23 ? s1 + 1 : 23;
    const float msc = 0.5f / 23.f;
    auto spl = [&](int row) -> float {
        float pk = cp[row][seg], pk1 = cp[row][s1];
        float mk  = msc * (pk1 - cp[row][sm1]);
        float mk1 = msc * (cp[row][sp2] - pk);
        return h00 * pk + h10 * mk + h01 * pk1 + h11 * mk1;
    };
    #pragma unroll
    for (int r = 0; r < 16; ++r) U[((size_t)b * 16 + r) * 512 + j] = sw[r] * spl(r);
    #pragma unroll
    for (int r = 0; r < 16; ++r) V[((size_t)b * 16 + r) * 512 + j] = spl(16 + r);
    float dx = sw[32];
    #pragma unroll
    for (int r = 0; r < 8; ++r) dx += sw[16 + r] * spl(32 + r);
    dxv[(size_t)b * 512 + j] = dx;
    float dy = 0.f;
    #pragma unroll
    for (int r = 0; r < 8; ++r) dy += sw[24 + r] * spl(40 + r);
    dyv[(size_t)b * 512 + j] = dy;
}

// ---------- depth: out[b,h,w] = sum_r U'[b,r,w]*V[b,r,h] + dx[w] + dy[h]  (U' pre-scaled, dx includes gbias)
__global__ __launch_bounds__(256) void depth_kernel(
    const float* __restrict__ U, const float* __restrict__ V,
    const float* __restrict__ dxv, const float* __restrict__ dyv,
    float* __restrict__ out)
{
    __shared__ __align__(16) float u_s[16][132];
    __shared__ __align__(16) float v_s[16][132];
    __shared__ float dx_s[128], dy_s[128];
    const int tid = threadIdx.x;
    const int b = blockIdx.z, h0 = blockIdx.y * 128, w0 = blockIdx.x * 128;
    #pragma unroll
    for (int j = 0; j < 8; ++j) {
        int idx = tid + j * 256;
        int r = idx >> 7, w = idx & 127;
        u_s[r][w] = U[((size_t)b * 16 + r) * 512 + w0 + w];
        v_s[r][w] = V[((size_t)b * 16 + r) * 512 + h0 + w];
    }
    if (tid < 128) dx_s[tid] = dxv[(size_t)b * 512 + w0 + tid];
    else           dy_s[tid - 128] = dyv[(size_t)b * 512 + h0 + tid - 128];
    __syncthreads();
    const int tw = tid & 15, th = tid >> 4;
    float acc[8][8];
    #pragma unroll
    for (int i = 0; i < 8; ++i)
        #pragma unroll
        for (int j = 0; j < 8; ++j) acc[i][j] = 0.f;
    #pragma unroll
    for (int r = 0; r < 16; ++r) {
        float4 va0 = *(const float4*)&v_s[r][th * 8];
        float4 va1 = *(const float4*)&v_s[r][th * 8 + 4];
        float4 ub0 = *(const float4*)&u_s[r][tw * 8];
        float4 ub1 = *(const float4*)&u_s[r][tw * 8 + 4];
        float va[8] = {va0.x, va0.y, va0.z, va0.w, va1.x, va1.y, va1.z, va1.w};
        float ub[8] = {ub0.x, ub0.y, ub0.z, ub0.w, ub1.x, ub1.y, ub1.z, ub1.w};
        #pragma unroll
        for (int i = 0; i < 8; ++i)
            #pragma unroll
            for (int j = 0; j < 8; ++j)
                acc[i][j] += va[i] * ub[j];
    }
    #pragma unroll
    for (int i = 0; i < 8; ++i) {
        float dyh = dy_s[th * 8 + i];
        float* op = out + (size_t)b * 262144 + (size_t)(h0 + th * 8 + i) * 512 + w0 + tw * 8;
        float4 o0, o1;
        o0.x = acc[i][0] + dx_s[tw * 8 + 0] + dyh;
        o0.y = acc[i][1] + dx_s[tw * 8 + 1] + dyh;
        o0.z = acc[i][2] + dx_s[tw * 8 + 2] + dyh;
        o0.w = acc[i][3] + dx_s[tw * 8 + 3] + dyh;
        o1.x = acc[i][4] + dx_s[tw * 8 + 4] + dyh;
        o1.y = acc[i][5] + dx_s[tw * 8 + 5] + dyh;
        o1.z = acc[i][6] + dx_s[tw * 8 + 6] + dyh;
        o1.w = acc[i][7] + dx_s[tw * 8 + 7] + dyh;
        *(float4*)op = o0;
        *(float4*)(op + 4) = o1;
    }
}

// ---------- host ----------
extern "C" void kernel_launch(void* const* d_in, const int* in_sizes, int n_in,
                              void* d_out, int out_size, void* d_ws, size_t ws_size,
                              hipStream_t stream) {
    const float* in_h     = (const float*)d_in[0];
    const float* rank_emb = (const float*)d_in[1];
    const float* st_w1    = (const float*)d_in[2];
    const float* st_b1    = (const float*)d_in[3];
    const float* st_w2    = (const float*)d_in[4];
    const float* st_b2    = (const float*)d_in[5];
    const float* rm_w1    = (const float*)d_in[6];
    const float* rm_b1    = (const float*)d_in[7];
    const float* rm_w2    = (const float*)d_in[8];
    const float* rm_b2    = (const float*)d_in[9];
    const float* mx_w1    = (const float*)d_in[10];
    const float* mx_b1    = (const float*)d_in[11];
    const float* mx_w2    = (const float*)d_in[12];
    const float* mx_b2    = (const float*)d_in[13];
    const float* my_w1    = (const float*)d_in[14];
    const float* my_b1    = (const float*)d_in[15];
    const float* my_w2    = (const float*)d_in[16];
    const float* my_b2    = (const float*)d_in[17];
    const float* ax_w1    = (const float*)d_in[18];
    const float* ax_b1    = (const float*)d_in[19];
    const float* ax_w2    = (const float*)d_in[20];
    const float* ax_b2    = (const float*)d_in[21];
    const float* ay_w1    = (const float*)d_in[22];
    const float* ay_b1    = (const float*)d_in[23];
    const float* ay_w2    = (const float*)d_in[24];
    const float* ay_b2    = (const float*)d_in[25];
    const float* mult_w   = (const float*)d_in[26];
    const float* addx_w   = (const float*)d_in[27];
    const float* addy_w   = (const float*)d_in[28];
    const float* gbias    = (const float*)d_in[29];
    (void)in_sizes; (void)n_in; (void)out_size; (void)ws_size;

    float* ws      = (float*)d_ws;
    float* hid1    = ws;                 // 64x512
    float* shared_ = ws + 32768;         // 64x256
    float* re_bias = ws + 49152;         // 24x256
    float* rfh     = ws + 55296;         // 64x24x256
    float* rf      = ws + 448512;        // 64x24x256
    float* hcat    = ws + 841728;        // 64x48x256
    float* Pcat    = ws + 1628160;       // 64x48x24
    float* U       = ws + 1701888;       // 64x16x512
    float* V       = ws + 2226176;       // 64x16x512
    float* dxv     = ws + 2750464;       // 64x512
    float* dyv     = ws + 2783232;       // 64x512

    const int BIG = 1 << 30;
    // zero all atomic-accumulated regions (through Pcat end = 1701888 floats)
    hipMemsetAsync(ws, 0, (size_t)1701888 * sizeof(float), stream);

    prebias_kernel<<<24, 256, 0, stream>>>(rank_emb, rm_w1, rm_b1, re_bias);

    {   // L1: h @ st_w1 -> hid1 (pre-activation), K=768, N=512
        GemmArgs a{}; a.W[0] = st_w1; a.bias[0] = st_b1;
        a.gstart[0] = 0; a.gstart[1] = BIG; a.gstart[2] = BIG; a.gstart[3] = BIG; a.gstart[4] = BIG;
        a.in_roff[0] = 0; a.rmul[0] = 0; a.wstride[0] = 768 * 512;
        gemm_kernel<false><<<dim3(8, 1, 6), 256, 0, stream>>>(
            in_h, hid1, 768, 128, 512, 768, 512, 0, a);
    }
    {   // L2: leaky(hid1) @ st_w2 -> shared_, K=512, N=256
        GemmArgs a{}; a.W[0] = st_w2; a.bias[0] = st_b2;
        a.gstart[0] = 0; a.gstart[1] = BIG; a.gstart[2] = BIG; a.gstart[3] = BIG; a.gstart[4] = BIG;
        a.in_roff[0] = 0; a.rmul[0] = 0; a.wstride[0] = 512 * 256;
        gemm_kernel<true><<<dim3(4, 1, 4), 256, 0, stream>>>(
            hid1, shared_, 512, 128, 256, 512, 256, 0, a);
    }
    {   // L3: shared_ @ rm_w1[:, :256, :] + re_bias -> rfh (pre-act), 24 ranks, K=256
        GemmArgs a{}; a.W[0] = rm_w1; a.bias[0] = re_bias;
        a.gstart[0] = 0; a.gstart[1] = BIG; a.gstart[2] = BIG; a.gstart[3] = BIG; a.gstart[4] = BIG;
        a.in_roff[0] = 0; a.rmul[0] = 0; a.wstride[0] = 512 * 256;
        gemm_kernel<false><<<dim3(4, 24, 2), 256, 0, stream>>>(
            shared_, rfh, 256, 128, 256, 256, 6144, 256, a);
    }
    {   // L4: leaky(rfh) @ rm_w2 -> rf, 24 ranks
        GemmArgs a{}; a.W[0] = rm_w2; a.bias[0] = rm_b2;
        a.gstart[0] = 0; a.gstart[1] = BIG; a.gstart[2] = BIG; a.gstart[3] = BIG; a.gstart[4] = BIG;
        a.in_roff[0] = 0; a.rmul[0] = 1; a.wstride[0] = 256 * 256;
        gemm_kernel<true><<<dim3(4, 24, 2), 256, 0, stream>>>(
            rfh, rf, 256, 128, 256, 6144, 6144, 256, a);
    }
    {   // G2: rf -> hcat (pre-act hidden of 4 head groups), 48 rows
        GemmArgs a{};
        a.W[0] = mx_w1; a.W[1] = my_w1; a.W[2] = ax_w1; a.W[3] = ay_w1;
        a.bias[0] = mx_b1; a.bias[1] = my_b1; a.bias[2] = ax_b1; a.bias[3] = ay_b1;
        a.gstart[0] = 0; a.gstart[1] = 16; a.gstart[2] = 32; a.gstart[3] = 40; a.gstart[4] = 48;
        a.in_roff[0] = 0; a.in_roff[1] = 0; a.in_roff[2] = 16; a.in_roff[3] = 16;
        a.rmul[0] = 1; a.rmul[1] = 1; a.rmul[2] = 1; a.rmul[3] = 1;
        a.wstride[0] = 65536; a.wstride[1] = 65536; a.wstride[2] = 65536; a.wstride[3] = 65536;
        gemm_kernel<false><<<dim3(4, 48, 2), 256, 0, stream>>>(
            rf, hcat, 256, 128, 256, 6144, 12288, 256, a);
    }
    {   // G3: leaky(hcat) -> Pcat (B,48,24)
        GemmArgs a{};
        a.W[0] = mx_w2; a.W[1] = my_w2; a.W[2] = ax_w2; a.W[3] = ay_w2;
        a.bias[0] = mx_b2; a.bias[1] = my_b2; a.bias[2] = ax_b2; a.bias[3] = ay_b2;
        a.gstart[0] = 0; a.gstart[1] = 16; a.gstart[2] = 32; a.gstart[3] = 40; a.gstart[4] = 48;
        a.in_roff[0] = 0; a.in_roff[1] = 16; a.in_roff[2] = 32; a.in_roff[3] = 40;
        a.rmul[0] = 1; a.rmul[1] = 1; a.rmul[2] = 1; a.rmul[3] = 1;
        a.wstride[0] = 6144; a.wstride[1] = 6144; a.wstride[2] = 6144; a.wstride[3] = 6144;
        gemm24_kernel<true><<<dim3(1, 48, 2), 128, 0, stream>>>(hcat, Pcat, 128, 12288, a);
    }
    spline_kernel<<<64, 512, 0, stream>>>(Pcat, mult_w, addx_w, addy_w, gbias, U, V, dxv, dyv);
    depth_kernel<<<dim3(4, 4, 64), 256, 0, stream>>>(U, V, dxv, dyv, (float*)d_out);
}